// Round 9
// baseline (112.931 us; speedup 1.0000x reference)
//
#include <hip/hip_runtime.h>

// TF-IDF: out[b,v] = cnt[b,v] * idf[v] / sum_s idf[x[b,s]]
//   x: (512,1024) int32, idf: (50257,) fp32, out: (512,50257) fp32
//
// Round 9 = Round 8 write machinery (u16-pair-packed counts, per-quad
// ds_read_b64 + idf dwordx4 + packed float4 store) with the vocab split in
// HALF so TWO 1024-thread blocks fit per CU:
//   LDS = 12,568 packed words (50,272 B) + red = 50.3 KB -> 2 resident
//   blocks/CU = 32 waves/CU (max). One resident's histogram phase (LDS
//   zero + the row's 1024 divergent idf gathers + barrier) overlaps the
//   other's store drain -- R8 had 1 resident (100.5 KB LDS) and paid that
//   phase with the store pipe idle, twice.
// Cost: inv_n is recomputed per block (needs the full row), so gathers
// double vs R8 -- but they hide under the co-resident block's stores.
// Unlike failed R3/R6 segmentations: 1024-thr blocks (16 waves of store
// issue each) and only a 2x gather multiplier (vs 4-7x).
// Every output byte written exactly once; no global atomics.

constexpr int VOCAB  = 50257;
constexpr int SEQ    = 1024;
constexpr int BATCH  = 512;
constexpr int NT     = 1024;
constexpr int SEGV   = (VOCAB + 1) / 2;            // 25129 vocab ids / segment
constexpr int SWORDS = (SEGV + 1) / 2;             // 12565 packed u32 words
constexpr int SWORDS4 = ((SWORDS + 3) / 4) * 4;    // 12568 -> 50,272 B LDS

struct __attribute__((packed)) f4p { float4 v; };  // relaxed-alignment 16B ls

__global__ __launch_bounds__(NT, 8)   // 8 waves/EU = 2 blocks/CU; caps VGPR<=64
void tfidf_kernel(const int* __restrict__ x,
                  const float* __restrict__ idf,
                  float* __restrict__ out) {
    __shared__ __align__(16) unsigned int cnt[SWORDS4];
    __shared__ float red[NT / 64];

    const int blk = blockIdx.x;
    const int b   = blk >> 1;          // row (adjacent blocks share x row +
    const int s   = blk & 1;           //  idf gathers in L1/L2)
    const int tid = threadIdx.x;

    const int lo  = s * SEGV;                          // 0 or 25129
    const int len = s ? (VOCAB - SEGV) : SEGV;         // 25128 or 25129

    // coalesced token load first (latency hides under LDS zeroing)
    const int tok = x[(size_t)b * SEQ + tid];

    // zero the packed half-vocab histogram (uint4, ~3 iters/thread)
    {
        uint4* z = (uint4*)cnt;
        const uint4 z4 = make_uint4(0u, 0u, 0u, 0u);
        for (int i = tid; i < SWORDS4 / 4; i += NT) z[i] = z4;
    }

    // one divergent gather per token (required for inv_n = full-row sum)
    const float my_idf = idf[tok];
    __syncthreads();                      // zeroing complete

    // histogram of in-segment tokens: two u16 counts per u32 word
    {
        const unsigned t = (unsigned)(tok - lo);       // covers tok < lo too
        if (t < (unsigned)len)
            atomicAdd(&cnt[t >> 1], (t & 1) ? 65536u : 1u);
    }

    // normalizer
    float v = my_idf;
    #pragma unroll
    for (int off = 32; off > 0; off >>= 1) v += __shfl_down(v, off, 64);
    if ((tid & 63) == 0) red[tid >> 6] = v;
    __syncthreads();                      // histogram + partials complete
    float nsum = 0.0f;
    #pragma unroll
    for (int w = 0; w < NT / 64; ++w) nsum += red[w];
    const float inv_n = 1.0f / nsum;

    // ---- write phase: per local quad c -> vocab ids lo+4c .. lo+4c+3 ----
    //   1 ds_read_b64 (4 packed counts) + 1 idf 16B load + 1 16B store.
    //   idf/out pointers are only 4B-aligned in general (lo=25129 is odd
    //   offset, row starts at b*50257) -> packed-struct 16B accesses; the
    //   wave's span stays contiguous so coalescing holds (validated R8).
    float* __restrict__ orow = out + (size_t)b * VOCAB + lo;
    const f4p* __restrict__ idf4 = (const f4p*)(idf + lo);
    f4p* __restrict__ o4 = (f4p*)orow;
    const int n4 = len >> 2;                           // 6282 quads

    for (int c = tid; c < n4; c += NT) {               // ~6.1 indep iters
        const uint2  w = *(const uint2*)&cnt[2 * c];   // ds_read_b64
        const float4 f = idf4[c].v;
        float4 r;
        r.x = (float)(w.x & 0xffffu) * f.x * inv_n;
        r.y = (float)(w.x >> 16)     * f.y * inv_n;
        r.z = (float)(w.y & 0xffffu) * f.z * inv_n;
        r.w = (float)(w.y >> 16)     * f.w * inv_n;
        o4[c].v = r;                                   // 16B store
    }
    if (tid == 0 && (len & 3)) {        // s==0 tail: local id 25128 (even->low)
        const int i = n4 << 2;
        orow[i] = (float)(cnt[i >> 1] & 0xffffu) * idf[lo + i] * inv_n;
    }
}

extern "C" void kernel_launch(void* const* d_in, const int* in_sizes, int n_in,
                              void* d_out, int out_size, void* d_ws, size_t ws_size,
                              hipStream_t stream) {
    const int*   x   = (const int*)d_in[0];
    const float* idf = (const float*)d_in[1];
    float*       out = (float*)d_out;
    tfidf_kernel<<<dim3(BATCH * 2), dim3(NT), 0, stream>>>(x, idf, out);
}

// Round 10
// 111.289 us; speedup vs baseline: 1.0148x; 1.0148x over previous
//
#include <hip/hip_runtime.h>

// TF-IDF: out[b,v] = cnt[b,v] * idf[v] / sum_s idf[x[b,s]]
//   x: (512,1024) int32, idf: (50257,) fp32, out: (512,50257) fp32
//
// FINAL (= Round 8, the measured optimum at 110.0 us; the NSEG ladder
// 1/2/4/7 segments -> 110.0/112.9/114.2/120.4 us shows cost is monotone in
// segment count, so NSEG=1 wins):
//   one 1024-thread block per row; full-vocab u16-pair-packed LDS histogram
//   (100.5 KB, max count 1024 < 2^16 so odd-id +65536 never carries);
//   ONE divergent idf gather per token; write phase per aligned vocab quad:
//   1 ds_read_b64 (4 packed counts) + 1 idf dwordx4 + 1 packed 16B store.
//   Every output byte written exactly once; no global atomics.

constexpr int VOCAB   = 50257;
constexpr int SEQ     = 1024;
constexpr int BATCH   = 512;
constexpr int HWORDS  = (VOCAB + 1) / 2;          // 25129 packed u32 words
constexpr int HWORDS4 = ((HWORDS + 3) / 4) * 4;   // 25132 -> 100,528 B LDS
constexpr int NT      = 1024;                     // one token per thread
constexpr int NGROUP  = VOCAB >> 2;               // 12564 aligned vocab quads

struct __attribute__((packed)) f4p { float4 v; };  // relaxed-alignment store

__global__ __launch_bounds__(NT)
void tfidf_kernel(const int* __restrict__ x,
                  const float* __restrict__ idf,
                  float* __restrict__ out) {
    __shared__ __align__(16) unsigned int cnt[HWORDS4];
    __shared__ float red[NT / 64];

    const int b   = blockIdx.x;
    const int tid = threadIdx.x;

    // token load first (global latency hides under LDS zeroing)
    const int tok = x[(size_t)b * SEQ + tid];

    // zero the packed histogram (uint4, ~6 iters/thread)
    {
        uint4* z = (uint4*)cnt;
        const uint4 z4 = make_uint4(0u, 0u, 0u, 0u);
        for (int i = tid; i < HWORDS4 / 4; i += NT) z[i] = z4;
    }

    // the ONLY divergent gather: idf[tok], once per token
    const float my_idf = idf[tok];
    __syncthreads();                       // zeroing complete

    // histogram: two u16 counts per u32 word; max count 1024 < 2^16 -> no carry
    atomicAdd(&cnt[tok >> 1], (tok & 1) ? 65536u : 1u);

    // normalizer
    float v = my_idf;
    #pragma unroll
    for (int off = 32; off > 0; off >>= 1) v += __shfl_down(v, off, 64);
    if ((tid & 63) == 0) red[tid >> 6] = v;
    __syncthreads();                       // histogram + partials complete
    float nsum = 0.0f;
    #pragma unroll
    for (int w = 0; w < NT / 64; ++w) nsum += red[w];
    const float inv_n = 1.0f / nsum;

    // ---- write phase: vocab-aligned quads ------------------------------
    float* __restrict__ orow = out + (size_t)b * VOCAB;
    const float4* __restrict__ idf4 = (const float4*)idf;   // 16B-aligned
    f4p* __restrict__ o4 = (f4p*)orow;                      // 4B-aligned ok

    for (int c = tid; c < NGROUP; c += NT) {   // ~12.3 independent iters
        const uint2  w = *(const uint2*)&cnt[2 * c];        // ds_read_b64
        const float4 f = idf4[c];                           // dwordx4 load
        float4 r;
        r.x = (float)(w.x & 0xffffu) * f.x * inv_n;
        r.y = (float)(w.x >> 16)     * f.y * inv_n;
        r.z = (float)(w.y & 0xffffu) * f.z * inv_n;
        r.w = (float)(w.y >> 16)     * f.w * inv_n;
        o4[c].v = r;                                        // dwordx4 store
    }
    if (tid == 0) {                            // tail: vi = 50256 (even -> low)
        orow[VOCAB - 1] =
            (float)(cnt[(VOCAB - 1) >> 1] & 0xffffu) * idf[VOCAB - 1] * inv_n;
    }
}

extern "C" void kernel_launch(void* const* d_in, const int* in_sizes, int n_in,
                              void* d_out, int out_size, void* d_ws, size_t ws_size,
                              hipStream_t stream) {
    const int*   x   = (const int*)d_in[0];
    const float* idf = (const float*)d_in[1];
    float*       out = (float*)d_out;
    tfidf_kernel<<<dim3(BATCH), dim3(NT), 0, stream>>>(x, idf, out);
}